// Round 9
// baseline (129.004 us; speedup 1.0000x reference)
//
#include <hip/hip_runtime.h>
#include <math.h>

// Problem constants: B=8, S=1024, D=128 (fp32 in/out)
#define NB 8
#define NS 1024
#define ND 128
#define NC 64     // chunks
#define NL 16     // steps per chunk

// workspace layout (float offsets)
#define OFF_K  0u
#define OFF_Q  1048576u
#define OFF_V  2097152u
#define OFF_E  3145728u
#define OFF_GA 4194304u
#define OFF_GE 4202496u
#define OFF_GT 4210688u
#define OFF_W  4218880u
#define OFF_C  4227072u
#define OFF_P  4235264u   // scan scratch

// chunked-scan scratch
#define PL_A00 (OFF_P)
#define PL_A01 (OFF_P +  65536u)
#define PL_A10 (OFF_P + 131072u)
#define PL_A11 (OFF_P + 196608u)
#define PL_B0  (OFF_P + 262144u)
#define PL_B1  (OFF_P + 327680u)
#define PL_MST (OFF_P + 393216u)
#define PL_SST (OFF_P + 458752u)
#define PL_WCA (OFF_P + 524288u)
#define PL_WCB (OFF_P + 524800u)
#define PL_WCD (OFF_P + 525312u)
#define PL_WRQ (OFF_P + 525824u)
#define PL_WRP (OFF_P + 526336u)
#define PL_WRA (OFF_P + 526848u)
// bf16 W^T hi+lo (3 mats x 128 cols x 128 k each), ushort
#define OFF_WT (OFF_P + 532480u)
#define WT_LO  49152u   // ushort offset of lo plane

typedef short bf16x8 __attribute__((ext_vector_type(8)));
typedef float f32x4  __attribute__((ext_vector_type(4)));

static __device__ __forceinline__ unsigned short f2bf(float f) {
    unsigned u = __builtin_bit_cast(unsigned, f);
    unsigned r = (u + 0x7FFFu + ((u >> 16) & 1u)) >> 16;   // RNE
    return (unsigned short)r;
}
static __device__ __forceinline__ float bf2f(unsigned short h) {
    unsigned u = ((unsigned)h) << 16;
    return __builtin_bit_cast(float, u);
}
static __device__ __forceinline__ void split2(float a, float b,
                                              unsigned& hi, unsigned& lo) {
    unsigned short ah = f2bf(a), bh = f2bf(b);
    float ar = a - bf2f(ah), br = b - bf2f(bh);
    hi = (unsigned)ah | ((unsigned)bh << 16);
    lo = (unsigned)f2bf(ar) | ((unsigned)f2bf(br) << 16);
}

// ---------------------------------------------------------------------------
// wtprep: W[k][c] fp32 -> wtg hi/lo planes [m][c][k] bf16 (transposed).
// Also zeroes the M/S output tail (atomics accumulate into it later).
// ---------------------------------------------------------------------------
__global__ __launch_bounds__(256) void wtprep_kernel(
    const float* __restrict__ Wk, const float* __restrict__ Wv,
    const float* __restrict__ Wq, unsigned short* __restrict__ wtg,
    float* __restrict__ outMS)
{
    const int m    = blockIdx.x >> 4;
    const int cgrp = blockIdx.x & 15;
    const int tid  = threadIdx.x;
    const int cl   = tid >> 5;
    const int h    = tid & 31;
    const int c    = cgrp * 8 + cl;
    const float* W = (m == 0) ? Wk : (m == 1) ? Wv : Wq;

    float f[4];
#pragma unroll
    for (int i = 0; i < 4; ++i)
        f[i] = W[(h * 4 + i) * ND + c];
    uint2 hi, lo;
    split2(f[0], f[1], hi.x, lo.x);
    split2(f[2], f[3], hi.y, lo.y);
    const unsigned base = (unsigned)m * 16384u + (unsigned)c * 128u + (unsigned)h * 4u;
    *(uint2*)&wtg[base]         = hi;
    *(uint2*)&wtg[WT_LO + base] = lo;

    // zero outMS: 65536 float4s over 48*256 = 12288 threads
    const int gidx = blockIdx.x * 256 + tid;
    const float4 z = {0.f, 0.f, 0.f, 0.f};
#pragma unroll
    for (int l = 0; l < 6; ++l) {
        int i4 = gidx + l * 12288;
        if (i4 < 65536) ((float4*)outMS)[i4] = z;
    }
}

// ---------------------------------------------------------------------------
// proj_mfma: one of {k,v,q} = x @ W via split-bf16 MFMA 16x16x32
// (3 MFMA terms: hi*hi + hi*lo + lo*hi -> ~fp32 precision).
// grid 1536 = 3 mats x 256 row-tiles(32) x 2 col-halves(64).
// ---------------------------------------------------------------------------
__global__ __launch_bounds__(256) void proj_mfma(
    const float* __restrict__ x, const unsigned short* __restrict__ wtg,
    const float* __restrict__ Wg, const float* __restrict__ bg,
    float* __restrict__ Kb, float* __restrict__ Vb, float* __restrict__ Qb,
    float* __restrict__ ga, float* __restrict__ ge, float* __restrict__ gt)
{
    __shared__ unsigned short xs_hi[32 * 136];
    __shared__ unsigned short xs_lo[32 * 136];
    __shared__ unsigned short wt_hi[64 * 136];
    __shared__ unsigned short wt_lo[64 * 136];

    const int tid  = threadIdx.x;
    const int bid  = blockIdx.x;
    const int m    = bid >> 9;
    const int rt   = (bid >> 1) & 255;
    const int ch   = bid & 1;
    const int row0 = rt * 32;

    const float4* x4 = (const float4*)x;
#pragma unroll
    for (int l = 0; l < 4; ++l) {
        int idx = tid + l * 256;
        int r = idx >> 5, kq = idx & 31;
        float4 f = x4[(row0 + r) * 32 + kq];
        uint2 hi, lo;
        split2(f.x, f.y, hi.x, lo.x);
        split2(f.z, f.w, hi.y, lo.y);
        *(uint2*)&xs_hi[r * 136 + kq * 4] = hi;
        *(uint2*)&xs_lo[r * 136 + kq * 4] = lo;
    }
    const uint4* wh4 = (const uint4*)(wtg + m * 16384 + ch * 64 * 128);
    const uint4* wl4 = (const uint4*)(wtg + WT_LO + m * 16384 + ch * 64 * 128);
#pragma unroll
    for (int l = 0; l < 4; ++l) {
        int idx = tid + l * 256;
        int c = idx >> 4, u = idx & 15;
        *(uint4*)&wt_hi[c * 136 + u * 8] = wh4[c * 16 + u];
        *(uint4*)&wt_lo[c * 136 + u * 8] = wl4[c * 16 + u];
    }
    __syncthreads();

    const int wid  = tid >> 6;
    const int lane = tid & 63;
    const int rg   = wid >> 1;
    const int cg   = wid & 1;
    const int lrow = rg * 16 + (lane & 15);
    const int quad = lane >> 4;

    f32x4 acc[2];
    acc[0] = (f32x4){0.f, 0.f, 0.f, 0.f};
    acc[1] = (f32x4){0.f, 0.f, 0.f, 0.f};

#pragma unroll
    for (int kk = 0; kk < 4; ++kk) {
        bf16x8 ah = *(const bf16x8*)&xs_hi[lrow * 136 + kk * 32 + quad * 8];
        bf16x8 al = *(const bf16x8*)&xs_lo[lrow * 136 + kk * 32 + quad * 8];
#pragma unroll
        for (int ct = 0; ct < 2; ++ct) {
            int cl = cg * 32 + ct * 16 + (lane & 15);
            bf16x8 bh = *(const bf16x8*)&wt_hi[cl * 136 + kk * 32 + quad * 8];
            bf16x8 bl = *(const bf16x8*)&wt_lo[cl * 136 + kk * 32 + quad * 8];
            acc[ct] = __builtin_amdgcn_mfma_f32_16x16x32_bf16(ah, bh, acc[ct], 0, 0, 0);
            acc[ct] = __builtin_amdgcn_mfma_f32_16x16x32_bf16(ah, bl, acc[ct], 0, 0, 0);
            acc[ct] = __builtin_amdgcn_mfma_f32_16x16x32_bf16(al, bh, acc[ct], 0, 0, 0);
        }
    }

    float* dst = (m == 0) ? Kb : (m == 1) ? Vb : Qb;
#pragma unroll
    for (int ct = 0; ct < 2; ++ct) {
        int ocol = ch * 64 + cg * 32 + ct * 16 + (lane & 15);
#pragma unroll
        for (int r4 = 0; r4 < 4; ++r4) {
            int orow = row0 + rg * 16 + quad * 4 + r4;
            dst[orow * ND + ocol] = acc[ct][r4];
        }
    }

    if (m == 0 && ch == 0 && tid < 96) {
        int r = tid / 3, j = tid % 3;
        float z = bg[j];
        const float* xr = x + (row0 + r) * ND;
#pragma unroll 4
        for (int i = 0; i < ND; ++i)
            z = fmaf(xr[i], Wg[i * 3 + j], z);
        float gate = 1.0f / (1.0f + expf(-z));
        int row = row0 + r;
        float* gd = (j == 0) ? ga : (j == 1) ? ge : gt;
        gd[row] = gate;
    }
}

// ---------------------------------------------------------------------------
// Phase 1: per (b, chunk, d) compose the 16 per-step affine maps into (A, b).
// ---------------------------------------------------------------------------
__global__ __launch_bounds__(128) void scan_phase1(
    const float* __restrict__ Kb, const float* __restrict__ Vb,
    const float* __restrict__ ga, const float* __restrict__ ge,
    const float* __restrict__ gt, float* __restrict__ ws)
{
    __shared__ float la[NL], le[NL], lt[NL];
    const int tid = threadIdx.x;
    const int b   = blockIdx.x >> 6;
    const int c   = blockIdx.x & 63;
    const int t0  = c * NL;
    const int g0  = b * NS + t0;

    if (tid < 16)       la[tid]      = ga[g0 + tid];
    else if (tid < 32)  le[tid - 16] = ge[g0 + tid - 16];
    else if (tid < 48)  lt[tid - 32] = gt[g0 + tid - 32];
    __syncthreads();

    const int d = tid;
    float A00 = 1.f, A01 = 0.f, A10 = 0.f, A11 = 1.f, B0 = 0.f, B1 = 0.f;
    int base = g0 * ND + d;
#pragma unroll
    for (int t = 0; t < NL; ++t) {
        float k = Kb[base], v = Vb[base];
        float a = la[t], e = le[t], th = lt[t];
        float tk = th * k;
        float gg = -tk * k;
        float h  = tk * v;
        float p  = (1.0f - a) + gg;
        float u0 = e * A10;
        float u1 = e * A11;
        float u2 = fmaf(e, B1, h);
        float n00 = fmaf(p, A00, u0), n10 = fmaf(gg, A00, u0);
        float n01 = fmaf(p, A01, u1), n11 = fmaf(gg, A01, u1);
        float nb0 = fmaf(p, B0, u2),  nb1 = fmaf(gg, B0, u2);
        A00 = n00; A01 = n01; A10 = n10; A11 = n11; B0 = nb0; B1 = nb1;
        base += ND;
    }
    const int pidx = (b * NC + c) * ND + d;
    ws[PL_A00 + pidx] = A00;
    ws[PL_A01 + pidx] = A01;
    ws[PL_A10 + pidx] = A10;
    ws[PL_A11 + pidx] = A11;
    ws[PL_B0  + pidx] = B0;
    ws[PL_B1  + pidx] = B1;

    if (tid == 0) {
        float al = 1.f, be = 1.f, de = 0.f;
#pragma unroll
        for (int t = NL - 1; t >= 0; --t) {
            float e1 = le[t];
            float o1 = 1.0f - la[t];
            de = fmaf(e1, de, o1 * be);
            al *= e1;
            be *= o1;
        }
        ws[PL_WCA + b * NC + c] = al;
        ws[PL_WCB + b * NC + c] = be;
        ws[PL_WCD + b * NC + c] = de;
    }
}

// ---------------------------------------------------------------------------
// Phase 2: scan over chunks (states entering each chunk).
// ---------------------------------------------------------------------------
__global__ __launch_bounds__(64) void scan_phase2(float* __restrict__ ws)
{
    const int tid = threadIdx.x;
    if (blockIdx.x < 16) {
        const int b = blockIdx.x >> 1;
        const int d = (blockIdx.x & 1) * 64 + tid;
        float m = 0.f, s = 0.f;
        int idx = (b * NC) * ND + d;
#pragma unroll 4
        for (int c = 0; c < NC; ++c) {
            ws[PL_MST + idx] = m;
            ws[PL_SST + idx] = s;
            float A00 = ws[PL_A00 + idx], A01 = ws[PL_A01 + idx];
            float A10 = ws[PL_A10 + idx], A11 = ws[PL_A11 + idx];
            float B0  = ws[PL_B0  + idx], B1  = ws[PL_B1  + idx];
            float nm = fmaf(A00, m, fmaf(A01, s, B0));
            float ns = fmaf(A10, m, fmaf(A11, s, B1));
            m = nm; s = ns;
            idx += ND;
        }
    } else if (tid < 8) {
        const int b = tid;
        float Qp = 1.f, P = 1.f, A = 1.f;
        for (int c = NC - 1; c >= 0; --c) {
            ws[PL_WRQ + b * NC + c] = Qp;
            ws[PL_WRP + b * NC + c] = P;
            ws[PL_WRA + b * NC + c] = A;
            float al = ws[PL_WCA + b * NC + c];
            float be = ws[PL_WCB + b * NC + c];
            float de = ws[PL_WCD + b * NC + c];
            float nA = fmaf(al, A, de * P);
            Qp *= al; P *= be; A = nA;
        }
    }
}

// ---------------------------------------------------------------------------
// Phase 3: replay each chunk from its start state; emit y_t, err_t, w_t, c_t.
// ---------------------------------------------------------------------------
__global__ __launch_bounds__(128) void scan_phase3(
    const float* __restrict__ Kb, const float* __restrict__ Vb,
    const float* __restrict__ Qb,
    const float* __restrict__ ga, const float* __restrict__ ge,
    const float* __restrict__ gt,
    float* __restrict__ out, float* __restrict__ errb,
    float* __restrict__ wb,  float* __restrict__ cb,
    float* __restrict__ ws)
{
    __shared__ float la[NL], le[NL], lt[NL];
    const int tid = threadIdx.x;
    const int b   = blockIdx.x >> 6;
    const int c   = blockIdx.x & 63;
    const int t0  = c * NL;
    const int g0  = b * NS + t0;

    if (tid < 16)       la[tid]      = ga[g0 + tid];
    else if (tid < 32)  le[tid - 16] = ge[g0 + tid - 16];
    else if (tid < 48)  lt[tid - 32] = gt[g0 + tid - 32];
    __syncthreads();

    const int d = tid;
    const int pidx = (b * NC + c) * ND + d;
    float m = ws[PL_MST + pidx];
    float s = ws[PL_SST + pidx];
    int base = g0 * ND + d;
#pragma unroll
    for (int t = 0; t < NL; ++t) {
        float k = Kb[base], v = Vb[base], q = Qb[base];
        float a = la[t], e = le[t], th = lt[t];
        float err = fmaf(k, m, -v);
        out[base]  = q * m;
        errb[base] = err;
        float tk = th * k;
        float u  = fmaf(-(tk * k), m, tk * v);
        s = fmaf(e, s, u);
        m = fmaf(1.0f - a, m, s);
        base += ND;
    }

    if (tid == 0) {
        float Qp = ws[PL_WRQ + b * NC + c];
        float P  = ws[PL_WRP + b * NC + c];
        float A  = ws[PL_WRA + b * NC + c];
#pragma unroll
        for (int t = NL - 1; t >= 0; --t) {
            wb[g0 + t] = -lt[t] * Qp;
            cb[g0 + t] = -lt[t] * A;
            float e1 = le[t];
            float o1 = 1.0f - la[t];
            Qp *= e1;
            P  *= o1;
            A   = fmaf(e1, A, P);
        }
    }
}

// ---------------------------------------------------------------------------
// finalgemm: M/S final via fine split-K + atomicAdd.
// grid 2048 = 8b x 32tc(32 t each) x 8rg(16 rows). 256 threads (8 blocks/CU).
// ---------------------------------------------------------------------------
__global__ __launch_bounds__(256) void finalgemm_kernel(
    const float* __restrict__ Kb, const float* __restrict__ errb,
    const float* __restrict__ wb, const float* __restrict__ cb,
    float* __restrict__ outMS)
{
    __shared__ float ks[32 * 16];
    __shared__ float wcs[32 * 2];
    const int tid = threadIdx.x;
    const int bid = blockIdx.x;
    const int b   = bid >> 8;
    const int tc  = (bid >> 3) & 31;
    const int rg  = bid & 7;
    const int bt0 = b * NS + tc * 32;

    // stage ks: 32 t x 16 rows = 128 float4s
    if (tid < 128) {
        int tl = tid >> 2, r4 = tid & 3;
        *(float4*)&ks[tl * 16 + r4 * 4] =
            *(const float4*)&Kb[(bt0 + tl) * ND + rg * 16 + r4 * 4];
    }
    if (tid >= 224) {   // 32 threads, different wave than ks stagers
        int t = tid - 224;
        wcs[t * 2]     = wb[bt0 + t];
        wcs[t * 2 + 1] = cb[bt0 + t];
    }
    __syncthreads();

    const int j = tid & 127;
    const int h = tid >> 7;
    float accM[8], accS[8];
#pragma unroll
    for (int i = 0; i < 8; ++i) { accM[i] = 0.f; accS[i] = 0.f; }

    int ebase = bt0 * ND + j;
#pragma unroll 4
    for (int t = 0; t < 32; ++t) {
        float ej = errb[ebase];
        float2 wc = *(const float2*)&wcs[t * 2];
        float wej = wc.x * ej, cej = wc.y * ej;
        float4 k0 = *(const float4*)&ks[t * 16 + h * 8];
        float4 k1 = *(const float4*)&ks[t * 16 + h * 8 + 4];
        accS[0] = fmaf(k0.x, wej, accS[0]); accM[0] = fmaf(k0.x, cej, accM[0]);
        accS[1] = fmaf(k0.y, wej, accS[1]); accM[1] = fmaf(k0.y, cej, accM[1]);
        accS[2] = fmaf(k0.z, wej, accS[2]); accM[2] = fmaf(k0.z, cej, accM[2]);
        accS[3] = fmaf(k0.w, wej, accS[3]); accM[3] = fmaf(k0.w, cej, accM[3]);
        accS[4] = fmaf(k1.x, wej, accS[4]); accM[4] = fmaf(k1.x, cej, accM[4]);
        accS[5] = fmaf(k1.y, wej, accS[5]); accM[5] = fmaf(k1.y, cej, accM[5]);
        accS[6] = fmaf(k1.z, wej, accS[6]); accM[6] = fmaf(k1.z, cej, accM[6]);
        accS[7] = fmaf(k1.w, wej, accS[7]); accM[7] = fmaf(k1.w, cej, accM[7]);
        ebase += ND;
    }

    const int robase = rg * 16 + h * 8;
#pragma unroll
    for (int i = 0; i < 8; ++i) {
        int off = b * (ND * ND) + (robase + i) * ND + j;
        atomicAdd(&outMS[off], accM[i]);
        atomicAdd(&outMS[131072u + off], accS[i]);
    }
}

extern "C" void kernel_launch(void* const* d_in, const int* in_sizes, int n_in,
                              void* d_out, int out_size, void* d_ws, size_t ws_size,
                              hipStream_t stream) {
    const float* x  = (const float*)d_in[0];
    const float* Wk = (const float*)d_in[1];
    const float* Wv = (const float*)d_in[2];
    const float* Wq = (const float*)d_in[3];
    const float* Wg = (const float*)d_in[4];
    const float* bg = (const float*)d_in[5];
    float* out = (float*)d_out;
    float* ws  = (float*)d_ws;

    float* Kb  = ws + OFF_K;
    float* Qb  = ws + OFF_Q;
    float* Vb  = ws + OFF_V;
    float* Eb  = ws + OFF_E;
    float* ga  = ws + OFF_GA;
    float* ge  = ws + OFF_GE;
    float* gt  = ws + OFF_GT;
    float* wbf = ws + OFF_W;
    float* cbf = ws + OFF_C;
    float* outMS = out + 1048576u;
    unsigned short* wtg = (unsigned short*)(ws + OFF_WT);

    wtprep_kernel<<<48, 256, 0, stream>>>(Wk, Wv, Wq, wtg, outMS);
    proj_mfma<<<1536, 256, 0, stream>>>(x, wtg, Wg, bg,
                                        Kb, Vb, Qb, ga, ge, gt);
    scan_phase1<<<NB * NC, 128, 0, stream>>>(Kb, Vb, ga, ge, gt, ws);
    scan_phase2<<<17, 64, 0, stream>>>(ws);
    scan_phase3<<<NB * NC, 128, 0, stream>>>(Kb, Vb, Qb, ga, ge, gt,
                                             out, Eb, wbf, cbf, ws);
    finalgemm_kernel<<<2048, 256, 0, stream>>>(Kb, Eb, wbf, cbf, outMS);
}

// Round 10
// 117.942 us; speedup vs baseline: 1.0938x; 1.0938x over previous
//
#include <hip/hip_runtime.h>
#include <math.h>

// Problem constants: B=8, S=1024, D=128 (fp32 in/out)
#define NB 8
#define NS 1024
#define ND 128
#define NC 64     // chunks
#define NL 16     // steps per chunk

// workspace layout (float offsets)
#define OFF_K  0u
#define OFF_Q  1048576u
#define OFF_V  2097152u
#define OFF_E  3145728u
#define OFF_GA 4194304u
#define OFF_GE 4202496u
#define OFF_GT 4210688u
#define OFF_W  4218880u
#define OFF_C  4227072u
#define OFF_P  4235264u   // scan scratch

// chunked-scan scratch
#define PL_A00 (OFF_P)
#define PL_A01 (OFF_P +  65536u)
#define PL_A10 (OFF_P + 131072u)
#define PL_A11 (OFF_P + 196608u)
#define PL_B0  (OFF_P + 262144u)
#define PL_B1  (OFF_P + 327680u)
#define PL_MST (OFF_P + 393216u)
#define PL_SST (OFF_P + 458752u)
#define PL_WCA (OFF_P + 524288u)
#define PL_WCB (OFF_P + 524800u)
#define PL_WCD (OFF_P + 525312u)
#define PL_WRQ (OFF_P + 525824u)
#define PL_WRP (OFF_P + 526336u)
#define PL_WRA (OFF_P + 526848u)
// bf16 W^T hi+lo (3 mats x 128 cols x 128 k each), ushort
#define OFF_WT (OFF_P + 532480u)
#define WT_LO  49152u   // ushort offset of lo plane

typedef short bf16x8 __attribute__((ext_vector_type(8)));
typedef float f32x4  __attribute__((ext_vector_type(4)));

static __device__ __forceinline__ unsigned short f2bf(float f) {
    unsigned u = __builtin_bit_cast(unsigned, f);
    unsigned r = (u + 0x7FFFu + ((u >> 16) & 1u)) >> 16;   // RNE
    return (unsigned short)r;
}
static __device__ __forceinline__ float bf2f(unsigned short h) {
    unsigned u = ((unsigned)h) << 16;
    return __builtin_bit_cast(float, u);
}
static __device__ __forceinline__ void split2(float a, float b,
                                              unsigned& hi, unsigned& lo) {
    unsigned short ah = f2bf(a), bh = f2bf(b);
    float ar = a - bf2f(ah), br = b - bf2f(bh);
    hi = (unsigned)ah | ((unsigned)bh << 16);
    lo = (unsigned)f2bf(ar) | ((unsigned)f2bf(br) << 16);
}

// ---------------------------------------------------------------------------
// wtprep: W[k][c] fp32 -> wtg hi/lo planes [m][c][k] bf16 (transposed).
// Also zeroes the M/S output tail (atomics accumulate into it later).
// ---------------------------------------------------------------------------
__global__ __launch_bounds__(256) void wtprep_kernel(
    const float* __restrict__ Wk, const float* __restrict__ Wv,
    const float* __restrict__ Wq, unsigned short* __restrict__ wtg,
    float* __restrict__ outMS)
{
    const int m    = blockIdx.x >> 4;
    const int cgrp = blockIdx.x & 15;
    const int tid  = threadIdx.x;
    const int cl   = tid >> 5;
    const int h    = tid & 31;
    const int c    = cgrp * 8 + cl;
    const float* W = (m == 0) ? Wk : (m == 1) ? Wv : Wq;

    float f[4];
#pragma unroll
    for (int i = 0; i < 4; ++i)
        f[i] = W[(h * 4 + i) * ND + c];
    uint2 hi, lo;
    split2(f[0], f[1], hi.x, lo.x);
    split2(f[2], f[3], hi.y, lo.y);
    const unsigned base = (unsigned)m * 16384u + (unsigned)c * 128u + (unsigned)h * 4u;
    *(uint2*)&wtg[base]         = hi;
    *(uint2*)&wtg[WT_LO + base] = lo;

    // zero outMS: 65536 float4s over 48*256 = 12288 threads
    const int gidx = blockIdx.x * 256 + tid;
    const float4 z = {0.f, 0.f, 0.f, 0.f};
#pragma unroll
    for (int l = 0; l < 6; ++l) {
        int i4 = gidx + l * 12288;
        if (i4 < 65536) ((float4*)outMS)[i4] = z;
    }
}

// ---------------------------------------------------------------------------
// proj_mfma: one of {k,v,q} = x @ W via split-bf16 MFMA 16x16x32
// (3 MFMA terms: hi*hi + hi*lo + lo*hi -> ~fp32 precision).
// grid 1536 = 3 mats x 256 row-tiles(32) x 2 col-halves(64).
// ---------------------------------------------------------------------------
__global__ __launch_bounds__(256) void proj_mfma(
    const float* __restrict__ x, const unsigned short* __restrict__ wtg,
    const float* __restrict__ Wg, const float* __restrict__ bg,
    float* __restrict__ Kb, float* __restrict__ Vb, float* __restrict__ Qb,
    float* __restrict__ ga, float* __restrict__ ge, float* __restrict__ gt)
{
    __shared__ unsigned short xs_hi[32 * 136];
    __shared__ unsigned short xs_lo[32 * 136];
    __shared__ unsigned short wt_hi[64 * 136];
    __shared__ unsigned short wt_lo[64 * 136];

    const int tid  = threadIdx.x;
    const int bid  = blockIdx.x;
    const int m    = bid >> 9;
    const int rt   = (bid >> 1) & 255;
    const int ch   = bid & 1;
    const int row0 = rt * 32;

    const float4* x4 = (const float4*)x;
#pragma unroll
    for (int l = 0; l < 4; ++l) {
        int idx = tid + l * 256;
        int r = idx >> 5, kq = idx & 31;
        float4 f = x4[(row0 + r) * 32 + kq];
        uint2 hi, lo;
        split2(f.x, f.y, hi.x, lo.x);
        split2(f.z, f.w, hi.y, lo.y);
        *(uint2*)&xs_hi[r * 136 + kq * 4] = hi;
        *(uint2*)&xs_lo[r * 136 + kq * 4] = lo;
    }
    const uint4* wh4 = (const uint4*)(wtg + m * 16384 + ch * 64 * 128);
    const uint4* wl4 = (const uint4*)(wtg + WT_LO + m * 16384 + ch * 64 * 128);
#pragma unroll
    for (int l = 0; l < 4; ++l) {
        int idx = tid + l * 256;
        int c = idx >> 4, u = idx & 15;
        *(uint4*)&wt_hi[c * 136 + u * 8] = wh4[c * 16 + u];
        *(uint4*)&wt_lo[c * 136 + u * 8] = wl4[c * 16 + u];
    }
    __syncthreads();

    const int wid  = tid >> 6;
    const int lane = tid & 63;
    const int rg   = wid >> 1;
    const int cg   = wid & 1;
    const int lrow = rg * 16 + (lane & 15);
    const int quad = lane >> 4;

    f32x4 acc[2];
    acc[0] = (f32x4){0.f, 0.f, 0.f, 0.f};
    acc[1] = (f32x4){0.f, 0.f, 0.f, 0.f};

#pragma unroll
    for (int kk = 0; kk < 4; ++kk) {
        bf16x8 ah = *(const bf16x8*)&xs_hi[lrow * 136 + kk * 32 + quad * 8];
        bf16x8 al = *(const bf16x8*)&xs_lo[lrow * 136 + kk * 32 + quad * 8];
#pragma unroll
        for (int ct = 0; ct < 2; ++ct) {
            int cl = cg * 32 + ct * 16 + (lane & 15);
            bf16x8 bh = *(const bf16x8*)&wt_hi[cl * 136 + kk * 32 + quad * 8];
            bf16x8 bl = *(const bf16x8*)&wt_lo[cl * 136 + kk * 32 + quad * 8];
            acc[ct] = __builtin_amdgcn_mfma_f32_16x16x32_bf16(ah, bh, acc[ct], 0, 0, 0);
            acc[ct] = __builtin_amdgcn_mfma_f32_16x16x32_bf16(ah, bl, acc[ct], 0, 0, 0);
            acc[ct] = __builtin_amdgcn_mfma_f32_16x16x32_bf16(al, bh, acc[ct], 0, 0, 0);
        }
    }

    float* dst = (m == 0) ? Kb : (m == 1) ? Vb : Qb;
#pragma unroll
    for (int ct = 0; ct < 2; ++ct) {
        int ocol = ch * 64 + cg * 32 + ct * 16 + (lane & 15);
#pragma unroll
        for (int r4 = 0; r4 < 4; ++r4) {
            int orow = row0 + rg * 16 + quad * 4 + r4;
            dst[orow * ND + ocol] = acc[ct][r4];
        }
    }

    if (m == 0 && ch == 0 && tid < 96) {
        int r = tid / 3, j = tid % 3;
        float z = bg[j];
        const float* xr = x + (row0 + r) * ND;
#pragma unroll 4
        for (int i = 0; i < ND; ++i)
            z = fmaf(xr[i], Wg[i * 3 + j], z);
        float gate = 1.0f / (1.0f + expf(-z));
        int row = row0 + r;
        float* gd = (j == 0) ? ga : (j == 1) ? ge : gt;
        gd[row] = gate;
    }
}

// ---------------------------------------------------------------------------
// Phase 1: per (b, chunk, d) compose the 16 per-step affine maps into (A, b).
// ---------------------------------------------------------------------------
__global__ __launch_bounds__(128) void scan_phase1(
    const float* __restrict__ Kb, const float* __restrict__ Vb,
    const float* __restrict__ ga, const float* __restrict__ ge,
    const float* __restrict__ gt, float* __restrict__ ws)
{
    __shared__ float la[NL], le[NL], lt[NL];
    const int tid = threadIdx.x;
    const int b   = blockIdx.x >> 6;
    const int c   = blockIdx.x & 63;
    const int t0  = c * NL;
    const int g0  = b * NS + t0;

    if (tid < 16)       la[tid]      = ga[g0 + tid];
    else if (tid < 32)  le[tid - 16] = ge[g0 + tid - 16];
    else if (tid < 48)  lt[tid - 32] = gt[g0 + tid - 32];
    __syncthreads();

    const int d = tid;
    float A00 = 1.f, A01 = 0.f, A10 = 0.f, A11 = 1.f, B0 = 0.f, B1 = 0.f;
    int base = g0 * ND + d;
#pragma unroll
    for (int t = 0; t < NL; ++t) {
        float k = Kb[base], v = Vb[base];
        float a = la[t], e = le[t], th = lt[t];
        float tk = th * k;
        float gg = -tk * k;
        float h  = tk * v;
        float p  = (1.0f - a) + gg;
        float u0 = e * A10;
        float u1 = e * A11;
        float u2 = fmaf(e, B1, h);
        float n00 = fmaf(p, A00, u0), n10 = fmaf(gg, A00, u0);
        float n01 = fmaf(p, A01, u1), n11 = fmaf(gg, A01, u1);
        float nb0 = fmaf(p, B0, u2),  nb1 = fmaf(gg, B0, u2);
        A00 = n00; A01 = n01; A10 = n10; A11 = n11; B0 = nb0; B1 = nb1;
        base += ND;
    }
    const int pidx = (b * NC + c) * ND + d;
    ws[PL_A00 + pidx] = A00;
    ws[PL_A01 + pidx] = A01;
    ws[PL_A10 + pidx] = A10;
    ws[PL_A11 + pidx] = A11;
    ws[PL_B0  + pidx] = B0;
    ws[PL_B1  + pidx] = B1;

    if (tid == 0) {
        float al = 1.f, be = 1.f, de = 0.f;
#pragma unroll
        for (int t = NL - 1; t >= 0; --t) {
            float e1 = le[t];
            float o1 = 1.0f - la[t];
            de = fmaf(e1, de, o1 * be);
            al *= e1;
            be *= o1;
        }
        ws[PL_WCA + b * NC + c] = al;
        ws[PL_WCB + b * NC + c] = be;
        ws[PL_WCD + b * NC + c] = de;
    }
}

// ---------------------------------------------------------------------------
// Phase 2: scan over chunks (states entering each chunk).
// ---------------------------------------------------------------------------
__global__ __launch_bounds__(64) void scan_phase2(float* __restrict__ ws)
{
    const int tid = threadIdx.x;
    if (blockIdx.x < 16) {
        const int b = blockIdx.x >> 1;
        const int d = (blockIdx.x & 1) * 64 + tid;
        float m = 0.f, s = 0.f;
        int idx = (b * NC) * ND + d;
#pragma unroll 4
        for (int c = 0; c < NC; ++c) {
            ws[PL_MST + idx] = m;
            ws[PL_SST + idx] = s;
            float A00 = ws[PL_A00 + idx], A01 = ws[PL_A01 + idx];
            float A10 = ws[PL_A10 + idx], A11 = ws[PL_A11 + idx];
            float B0  = ws[PL_B0  + idx], B1  = ws[PL_B1  + idx];
            float nm = fmaf(A00, m, fmaf(A01, s, B0));
            float ns = fmaf(A10, m, fmaf(A11, s, B1));
            m = nm; s = ns;
            idx += ND;
        }
    } else if (tid < 8) {
        const int b = tid;
        float Qp = 1.f, P = 1.f, A = 1.f;
        for (int c = NC - 1; c >= 0; --c) {
            ws[PL_WRQ + b * NC + c] = Qp;
            ws[PL_WRP + b * NC + c] = P;
            ws[PL_WRA + b * NC + c] = A;
            float al = ws[PL_WCA + b * NC + c];
            float be = ws[PL_WCB + b * NC + c];
            float de = ws[PL_WCD + b * NC + c];
            float nA = fmaf(al, A, de * P);
            Qp *= al; P *= be; A = nA;
        }
    }
}

// ---------------------------------------------------------------------------
// Phase 3: replay each chunk from its start state; emit y_t, err_t, w_t, c_t.
// ---------------------------------------------------------------------------
__global__ __launch_bounds__(128) void scan_phase3(
    const float* __restrict__ Kb, const float* __restrict__ Vb,
    const float* __restrict__ Qb,
    const float* __restrict__ ga, const float* __restrict__ ge,
    const float* __restrict__ gt,
    float* __restrict__ out, float* __restrict__ errb,
    float* __restrict__ wb,  float* __restrict__ cb,
    float* __restrict__ ws)
{
    __shared__ float la[NL], le[NL], lt[NL];
    const int tid = threadIdx.x;
    const int b   = blockIdx.x >> 6;
    const int c   = blockIdx.x & 63;
    const int t0  = c * NL;
    const int g0  = b * NS + t0;

    if (tid < 16)       la[tid]      = ga[g0 + tid];
    else if (tid < 32)  le[tid - 16] = ge[g0 + tid - 16];
    else if (tid < 48)  lt[tid - 32] = gt[g0 + tid - 32];
    __syncthreads();

    const int d = tid;
    const int pidx = (b * NC + c) * ND + d;
    float m = ws[PL_MST + pidx];
    float s = ws[PL_SST + pidx];
    int base = g0 * ND + d;
#pragma unroll
    for (int t = 0; t < NL; ++t) {
        float k = Kb[base], v = Vb[base], q = Qb[base];
        float a = la[t], e = le[t], th = lt[t];
        float err = fmaf(k, m, -v);
        out[base]  = q * m;
        errb[base] = err;
        float tk = th * k;
        float u  = fmaf(-(tk * k), m, tk * v);
        s = fmaf(e, s, u);
        m = fmaf(1.0f - a, m, s);
        base += ND;
    }

    if (tid == 0) {
        float Qp = ws[PL_WRQ + b * NC + c];
        float P  = ws[PL_WRP + b * NC + c];
        float A  = ws[PL_WRA + b * NC + c];
#pragma unroll
        for (int t = NL - 1; t >= 0; --t) {
            wb[g0 + t] = -lt[t] * Qp;
            cb[g0 + t] = -lt[t] * A;
            float e1 = le[t];
            float o1 = 1.0f - la[t];
            Qp *= e1;
            P  *= o1;
            A   = fmaf(e1, A, P);
        }
    }
}

// ---------------------------------------------------------------------------
// finalgemm: M/S final via fine split-K + atomicAdd.  (round-6 proven config)
// grid 1024 = 8b x 16tc(64 t each) x 8rg(16 rows). 256 threads, 4 blocks/CU.
// ---------------------------------------------------------------------------
__global__ __launch_bounds__(256) void finalgemm_kernel(
    const float* __restrict__ Kb, const float* __restrict__ errb,
    const float* __restrict__ wb, const float* __restrict__ cb,
    float* __restrict__ outMS)
{
    __shared__ float ks[64 * 16];
    __shared__ float wcs[64 * 2];
    const int tid = threadIdx.x;
    const int bid = blockIdx.x;
    const int b   = bid >> 7;
    const int tc  = (bid >> 3) & 15;
    const int rg  = bid & 7;
    const int bt0 = b * NS + tc * 64;

    {
        int tl = tid >> 2, r4 = tid & 3;
        *(float4*)&ks[tl * 16 + r4 * 4] =
            *(const float4*)&Kb[(bt0 + tl) * ND + rg * 16 + r4 * 4];
    }
    if (tid < 64) {
        wcs[tid * 2]     = wb[bt0 + tid];
        wcs[tid * 2 + 1] = cb[bt0 + tid];
    }
    __syncthreads();

    const int j = tid & 127;
    const int h = tid >> 7;
    float accM[8], accS[8];
#pragma unroll
    for (int i = 0; i < 8; ++i) { accM[i] = 0.f; accS[i] = 0.f; }

    int ebase = bt0 * ND + j;
#pragma unroll 4
    for (int t = 0; t < 64; ++t) {
        float ej = errb[ebase];
        float2 wc = *(const float2*)&wcs[t * 2];
        float wej = wc.x * ej, cej = wc.y * ej;
        float4 k0 = *(const float4*)&ks[t * 16 + h * 8];
        float4 k1 = *(const float4*)&ks[t * 16 + h * 8 + 4];
        accS[0] = fmaf(k0.x, wej, accS[0]); accM[0] = fmaf(k0.x, cej, accM[0]);
        accS[1] = fmaf(k0.y, wej, accS[1]); accM[1] = fmaf(k0.y, cej, accM[1]);
        accS[2] = fmaf(k0.z, wej, accS[2]); accM[2] = fmaf(k0.z, cej, accM[2]);
        accS[3] = fmaf(k0.w, wej, accS[3]); accM[3] = fmaf(k0.w, cej, accM[3]);
        accS[4] = fmaf(k1.x, wej, accS[4]); accM[4] = fmaf(k1.x, cej, accM[4]);
        accS[5] = fmaf(k1.y, wej, accS[5]); accM[5] = fmaf(k1.y, cej, accM[5]);
        accS[6] = fmaf(k1.z, wej, accS[6]); accM[6] = fmaf(k1.z, cej, accM[6]);
        accS[7] = fmaf(k1.w, wej, accS[7]); accM[7] = fmaf(k1.w, cej, accM[7]);
        ebase += ND;
    }

    const int robase = rg * 16 + h * 8;
#pragma unroll
    for (int i = 0; i < 8; ++i) {
        int off = b * (ND * ND) + (robase + i) * ND + j;
        atomicAdd(&outMS[off], accM[i]);
        atomicAdd(&outMS[131072u + off], accS[i]);
    }
}

extern "C" void kernel_launch(void* const* d_in, const int* in_sizes, int n_in,
                              void* d_out, int out_size, void* d_ws, size_t ws_size,
                              hipStream_t stream) {
    const float* x  = (const float*)d_in[0];
    const float* Wk = (const float*)d_in[1];
    const float* Wv = (const float*)d_in[2];
    const float* Wq = (const float*)d_in[3];
    const float* Wg = (const float*)d_in[4];
    const float* bg = (const float*)d_in[5];
    float* out = (float*)d_out;
    float* ws  = (float*)d_ws;

    float* Kb  = ws + OFF_K;
    float* Qb  = ws + OFF_Q;
    float* Vb  = ws + OFF_V;
    float* Eb  = ws + OFF_E;
    float* ga  = ws + OFF_GA;
    float* ge  = ws + OFF_GE;
    float* gt  = ws + OFF_GT;
    float* wbf = ws + OFF_W;
    float* cbf = ws + OFF_C;
    float* outMS = out + 1048576u;
    unsigned short* wtg = (unsigned short*)(ws + OFF_WT);

    wtprep_kernel<<<48, 256, 0, stream>>>(Wk, Wv, Wq, wtg, outMS);
    proj_mfma<<<1536, 256, 0, stream>>>(x, wtg, Wg, bg,
                                        Kb, Vb, Qb, ga, ge, gt);
    scan_phase1<<<NB * NC, 128, 0, stream>>>(Kb, Vb, ga, ge, gt, ws);
    scan_phase2<<<17, 64, 0, stream>>>(ws);
    scan_phase3<<<NB * NC, 128, 0, stream>>>(Kb, Vb, Qb, ga, ge, gt,
                                             out, Eb, wbf, cbf, ws);
    finalgemm_kernel<<<1024, 256, 0, stream>>>(Kb, Eb, wbf, cbf, outMS);
}